// Round 1
// baseline (257.424 us; speedup 1.0000x reference)
//
#include <hip/hip_runtime.h>
#include <hip/hip_bf16.h>

#define NN 50000
#define NE 800000

// ---------------- k0: pack KAN weights: Wk[o][i*6+c] = {base_w[o][i], spline_w[o][i][k]*scaler[o][i]}
__global__ __launch_bounds__(256) void k0_pack(
    const float* __restrict__ base_w, const float* __restrict__ spline_w,
    const float* __restrict__ scaler, float* __restrict__ Wk) {
  int idx = blockIdx.x * 256 + threadIdx.x;  // o*64 + i
  if (idx >= 64 * 64) return;
  float sc = scaler[idx];
  float* dst = Wk + (size_t)(idx >> 6) * 384 + (size_t)(idx & 63) * 6;
  dst[0] = base_w[idx];
#pragma unroll
  for (int k = 0; k < 5; ++k) dst[1 + k] = spline_w[(size_t)idx * 5 + k] * sc;
}

// ---------------- k1: per-node edge aggregation (one wave per node)
// Sp[n][f] = (sum_e attn_e * ctx_e[f]) / max(deg,1);  aprime[n] = (sum attn)/max(deg,1); degw[n]=deg
__global__ __launch_bounds__(256) void k1_edge_agg(
    const float* __restrict__ contexts, const float* __restrict__ attn,
    const int* __restrict__ seg, float* __restrict__ Sp,
    float* __restrict__ aprime, float* __restrict__ degw) {
  int n = blockIdx.x * 4 + (threadIdx.x >> 6);
  int lane = threadIdx.x & 63;
  if (n >= NN) return;
  // lower_bound(n)
  int lo = 0, hi = NE;
  while (lo < hi) { int m = (lo + hi) >> 1; if (seg[m] < n) lo = m + 1; else hi = m; }
  int s = lo;
  // lower_bound(n+1), restricted to [s, NE)
  int lo2 = s, hi2 = NE;
  while (lo2 < hi2) { int m = (lo2 + hi2) >> 1; if (seg[m] < n + 1) lo2 = m + 1; else hi2 = m; }
  int e_end = lo2;

  float S = 0.f, A = 0.f;
  int e = s;
  for (; e + 2 <= e_end; e += 2) {
    float a0 = attn[e], a1 = attn[e + 1];
    float c0 = contexts[(size_t)e * 64 + lane];
    float c1 = contexts[(size_t)(e + 1) * 64 + lane];
    S += a0 * c0;
    S += a1 * c1;
    A += a0 + a1;
  }
  if (e < e_end) {
    float a0 = attn[e];
    S += a0 * contexts[(size_t)e * 64 + lane];
    A += a0;
  }
  float deg = (float)(e_end - s);
  float inv = 1.f / fmaxf(deg, 1.f);
  Sp[(size_t)n * 64 + lane] = S * inv;
  if (lane == 0) { aprime[n] = A * inv; degw[n] = deg; }
}

// ---------------- k23: t = [x|Sp] @ [Wn|Wc]^T + bn + a'*bc ; upd = t @ Wu^T + bu
// 64-node tile per block, 256 threads (4 waves). Wave w computes h in [w*32,(w+1)*32) then o in [w*16,(w+1)*16).
__global__ __launch_bounds__(256) void k23_gemm(
    const float* __restrict__ x, const float* __restrict__ Sp,
    const float* __restrict__ aprime,
    const float* __restrict__ Wn, const float* __restrict__ bn,
    const float* __restrict__ Wc, const float* __restrict__ bc,
    const float* __restrict__ Wu, const float* __restrict__ bu,
    float* __restrict__ upd) {
  __shared__ __align__(16) float u[64][132];   // [node][f 0..127], f<64: x, f>=64: Sp
  __shared__ __align__(16) float tl[64][132];  // [node][h 0..127]
  __shared__ float ap[64];
  int tid = threadIdx.x;
  int n0 = blockIdx.x * 64;

  // stage u tile (float4)
  for (int q = tid; q < 64 * 32; q += 256) {
    int b = q >> 5, c = q & 31;
    int n = n0 + b;
    float4 val = make_float4(0.f, 0.f, 0.f, 0.f);
    if (n < NN) {
      if (c < 16) val = *(const float4*)(x + (size_t)n * 64 + c * 4);
      else        val = *(const float4*)(Sp + (size_t)n * 64 + (c - 16) * 4);
    }
    *(float4*)&u[b][c * 4] = val;
  }
  if (tid < 64) {
    int n = n0 + tid;
    ap[tid] = (n < NN) ? aprime[n] : 0.f;
  }
  __syncthreads();

  int wv = tid >> 6, lane = tid & 63;
  int nm = lane & 7, nh = lane >> 3;

  // ---- t-GEMM: acc[8 nodes][4 h], K=128
  {
    float acc[8][4];
#pragma unroll
    for (int i = 0; i < 8; ++i)
#pragma unroll
      for (int j = 0; j < 4; ++j) acc[i][j] = 0.f;
    const float4* Wn4 = (const float4*)Wn;
    const float4* Wc4 = (const float4*)Wc;
    int hbase = wv * 32 + nh * 4;
#pragma unroll 4
    for (int fb = 0; fb < 16; ++fb) {  // f = fb*4 in [0,64): x part vs Wn
      float4 w[4];
#pragma unroll
      for (int j = 0; j < 4; ++j) w[j] = Wn4[(size_t)(hbase + j) * 16 + fb];
#pragma unroll
      for (int i = 0; i < 8; ++i) {
        float4 uv = *(const float4*)&u[nm + 8 * i][fb * 4];
#pragma unroll
        for (int j = 0; j < 4; ++j)
          acc[i][j] += uv.x * w[j].x + uv.y * w[j].y + uv.z * w[j].z + uv.w * w[j].w;
      }
    }
#pragma unroll 4
    for (int fb = 0; fb < 16; ++fb) {  // f = 64 + fb*4: Sp part vs Wc
      float4 w[4];
#pragma unroll
      for (int j = 0; j < 4; ++j) w[j] = Wc4[(size_t)(hbase + j) * 16 + fb];
#pragma unroll
      for (int i = 0; i < 8; ++i) {
        float4 uv = *(const float4*)&u[nm + 8 * i][64 + fb * 4];
#pragma unroll
        for (int j = 0; j < 4; ++j)
          acc[i][j] += uv.x * w[j].x + uv.y * w[j].y + uv.z * w[j].z + uv.w * w[j].w;
      }
    }
#pragma unroll
    for (int j = 0; j < 4; ++j) {
      int h = hbase + j;
      float bnv = bn[h], bcv = bc[h];
#pragma unroll
      for (int i = 0; i < 8; ++i) {
        int b = nm + 8 * i;
        tl[b][h] = acc[i][j] + bnv + ap[b] * bcv;
      }
    }
  }
  __syncthreads();

  // ---- upd-GEMM: acc[8 nodes][2 o], K=128
  {
    float acc[8][2];
#pragma unroll
    for (int i = 0; i < 8; ++i) { acc[i][0] = 0.f; acc[i][1] = 0.f; }
    const float4* Wu4 = (const float4*)Wu;
    int obase = wv * 16 + nh * 2;
#pragma unroll 4
    for (int fb = 0; fb < 32; ++fb) {
      float4 w[2];
#pragma unroll
      for (int j = 0; j < 2; ++j) w[j] = Wu4[(size_t)(obase + j) * 32 + fb];
#pragma unroll
      for (int i = 0; i < 8; ++i) {
        float4 tv = *(const float4*)&tl[nm + 8 * i][fb * 4];
#pragma unroll
        for (int j = 0; j < 2; ++j)
          acc[i][j] += tv.x * w[j].x + tv.y * w[j].y + tv.z * w[j].z + tv.w * w[j].w;
      }
    }
    float* updl = &u[0][0];  // reuse u as [64][68] upd tile
#pragma unroll
    for (int j = 0; j < 2; ++j) {
      int o = obase + j;
      float buv = bu[o];
#pragma unroll
      for (int i = 0; i < 8; ++i) {
        int b = nm + 8 * i;
        updl[b * 68 + o] = acc[i][j] + buv;
      }
    }
  }
  __syncthreads();

  // coalesced store of upd tile
  const float* updl = &u[0][0];
  for (int q = tid; q < 64 * 64; q += 256) {
    int b = q >> 6, o = q & 63;
    int n = n0 + b;
    if (n < NN) upd[(size_t)n * 64 + o] = updl[b * 68 + o];
  }
}

// ---------------- k4: KAN head. v[b][i*6+c] = {silu(upd), bases[0..4]}; out = v @ Wk^T, where(deg>0, ., x)
__global__ __launch_bounds__(256) void k4_kan(
    const float* __restrict__ upd, const float* __restrict__ Wk,
    const float* __restrict__ degw, const float* __restrict__ xin,
    const float* __restrict__ gridp, float* __restrict__ out) {
  __shared__ __align__(16) float v[32][388];
  __shared__ float degl[32];
  int tid = threadIdx.x;
  int n0 = blockIdx.x * 32;

  float g[8];
#pragma unroll
  for (int j = 0; j < 8; ++j) g[j] = gridp[j];  // all grid rows identical; use row 0
  float r1[7], r2[6];
#pragma unroll
  for (int j = 0; j < 7; ++j) r1[j] = 1.f / (g[j + 1] - g[j]);
#pragma unroll
  for (int j = 0; j < 6; ++j) r2[j] = 1.f / (g[j + 2] - g[j]);

  // stage + nonlinear transform
  for (int q = tid; q < 32 * 64; q += 256) {
    int b = q >> 6, i = q & 63;
    int n = n0 + b;
    float xv = (n < NN) ? upd[(size_t)n * 64 + i] : 0.f;
    float sil = xv / (1.f + __expf(-xv));
    float b0[7], b1[6], b2[5];
#pragma unroll
    for (int j = 0; j < 7; ++j) b0[j] = (xv >= g[j] && xv < g[j + 1]) ? 1.f : 0.f;
#pragma unroll
    for (int j = 0; j < 6; ++j)
      b1[j] = (xv - g[j]) * r1[j] * b0[j] + (g[j + 2] - xv) * r1[j + 1] * b0[j + 1];
#pragma unroll
    for (int j = 0; j < 5; ++j)
      b2[j] = (xv - g[j]) * r2[j] * b1[j] + (g[j + 3] - xv) * r2[j + 1] * b1[j + 1];
    float* dst = &v[b][i * 6];
    dst[0] = sil;
#pragma unroll
    for (int k = 0; k < 5; ++k) dst[1 + k] = b2[k];
  }
  if (tid < 32) {
    int n = n0 + tid;
    degl[tid] = (n < NN) ? degw[n] : 1.f;
  }
  __syncthreads();

  int wv = tid >> 6, lane = tid & 63;
  int nm = lane & 7, nh = lane >> 3;
  int obase = wv * 16 + nh * 2;
  float acc[4][2];
#pragma unroll
  for (int i = 0; i < 4; ++i) { acc[i][0] = 0.f; acc[i][1] = 0.f; }
  const float4* Wk4 = (const float4*)Wk;
#pragma unroll 4
  for (int kb = 0; kb < 96; ++kb) {  // K = 384
    float4 w[2];
#pragma unroll
    for (int j = 0; j < 2; ++j) w[j] = Wk4[(size_t)(obase + j) * 96 + kb];
#pragma unroll
    for (int i = 0; i < 4; ++i) {
      float4 vv = *(const float4*)&v[nm + 8 * i][kb * 4];
#pragma unroll
      for (int j = 0; j < 2; ++j)
        acc[i][j] += vv.x * w[j].x + vv.y * w[j].y + vv.z * w[j].z + vv.w * w[j].w;
    }
  }
  __syncthreads();  // everyone done reading v; reuse as out tile [32][68]

  float* ot = &v[0][0];
#pragma unroll
  for (int j = 0; j < 2; ++j) {
#pragma unroll
    for (int i = 0; i < 4; ++i) {
      int b = nm + 8 * i, o = obase + j;
      float val = acc[i][j];
      if (degl[b] <= 0.f) {
        int n = n0 + b;
        if (n < NN) val = xin[(size_t)n * 64 + o];
      }
      ot[b * 68 + o] = val;
    }
  }
  __syncthreads();
  for (int q = tid; q < 32 * 64; q += 256) {
    int b = q >> 6, o = q & 63;
    int n = n0 + b;
    if (n < NN) out[(size_t)n * 64 + o] = ot[b * 68 + o];
  }
}

extern "C" void kernel_launch(void* const* d_in, const int* in_sizes, int n_in,
                              void* d_out, int out_size, void* d_ws, size_t ws_size,
                              hipStream_t stream) {
  const float* x        = (const float*)d_in[0];
  const float* contexts = (const float*)d_in[1];
  const float* attn     = (const float*)d_in[2];
  const int*   seg      = (const int*)d_in[3];
  const float* Wn       = (const float*)d_in[4];
  const float* bn       = (const float*)d_in[5];
  const float* Wc       = (const float*)d_in[6];
  const float* bc       = (const float*)d_in[7];
  const float* Wu       = (const float*)d_in[8];
  const float* bu       = (const float*)d_in[9];
  const float* base_w   = (const float*)d_in[10];
  const float* spline_w = (const float*)d_in[11];
  const float* scaler   = (const float*)d_in[12];
  const float* gridp    = (const float*)d_in[13];
  float* out = (float*)d_out;

  float* ws     = (float*)d_ws;
  float* Sp     = ws;                  // N*64
  float* aprime = Sp + 3200000;        // N
  float* degw   = aprime + 50000;      // N
  float* upd    = degw + 50000;        // N*64
  float* Wk     = upd + 3200000;       // 64*384

  k0_pack<<<16, 256, 0, stream>>>(base_w, spline_w, scaler, Wk);
  k1_edge_agg<<<12500, 256, 0, stream>>>(contexts, attn, seg, Sp, aprime, degw);
  k23_gemm<<<782, 256, 0, stream>>>(x, Sp, aprime, Wn, bn, Wc, bc, Wu, bu, upd);
  k4_kan<<<1563, 256, 0, stream>>>(upd, Wk, degw, x, gridp, out);
}

// Round 2
// 176.058 us; speedup vs baseline: 1.4622x; 1.4622x over previous
//
#include <hip/hip_runtime.h>
#include <hip/hip_bf16.h>

#define NN 50000
#define NE 800000

// ---------------- k0: pack KAN weights: Wk[o][i*6+c] = {base_w[o][i], spline_w[o][i][k]*scaler[o][i]}
__global__ __launch_bounds__(256) void k0_pack(
    const float* __restrict__ base_w, const float* __restrict__ spline_w,
    const float* __restrict__ scaler, float* __restrict__ Wk) {
  int idx = blockIdx.x * 256 + threadIdx.x;  // o*64 + i
  if (idx >= 64 * 64) return;
  float sc = scaler[idx];
  float* dst = Wk + (size_t)(idx >> 6) * 384 + (size_t)(idx & 63) * 6;
  dst[0] = base_w[idx];
#pragma unroll
  for (int k = 0; k < 5; ++k) dst[1 + k] = spline_w[(size_t)idx * 5 + k] * sc;
}

// ---------------- k_off: CSR offsets from sorted seg_ids. off[n] = first edge with seg >= n.
__global__ __launch_bounds__(256) void k_off(const int* __restrict__ seg, int* __restrict__ off) {
  int e = blockIdx.x * 256 + threadIdx.x;
  if (e >= NE) return;
  int s1 = seg[e];
  if (e == 0) {
    for (int n = 0; n <= s1; ++n) off[n] = 0;
  } else {
    int s0 = seg[e - 1];
    for (int n = s0 + 1; n <= s1; ++n) off[n] = e;
  }
  if (e == NE - 1) {
    for (int n = s1 + 1; n <= NN; ++n) off[n] = NE;
  }
}

// ---------------- k1: per-node edge aggregation (one wave per node, 4 edges per load)
// Sp[n][f] = (sum_e attn_e * ctx_e[f]) / max(deg,1);  aprime[n] = (sum attn)/max(deg,1); degw[n]=deg
__global__ __launch_bounds__(256) void k1_edge_agg(
    const float* __restrict__ contexts, const float* __restrict__ attn,
    const int* __restrict__ off, float* __restrict__ Sp,
    float* __restrict__ aprime, float* __restrict__ degw) {
  int n = blockIdx.x * 4 + (threadIdx.x >> 6);
  int lane = threadIdx.x & 63;
  if (n >= NN) return;
  int s = off[n];
  int e_end = off[n + 1];

  int sub = lane >> 4;   // which edge in the quad
  int fq = lane & 15;    // feature quad (4 floats)
  const float4* ctx4 = (const float4*)contexts;

  float4 S = make_float4(0.f, 0.f, 0.f, 0.f);
  float A = 0.f;
  int last = e_end - 1;
  for (int e0 = s; e0 < e_end; e0 += 8) {
    int ea = e0 + sub;
    int eb = e0 + 4 + sub;
    float aa = (ea < e_end) ? attn[ea] : 0.f;
    float ab = (eb < e_end) ? attn[eb] : 0.f;
    int ca = min(ea, last);
    int cb = min(eb, last);
    float4 va = ctx4[(size_t)ca * 16 + fq];
    float4 vb = ctx4[(size_t)cb * 16 + fq];
    S.x += aa * va.x + ab * vb.x;
    S.y += aa * va.y + ab * vb.y;
    S.z += aa * va.z + ab * vb.z;
    S.w += aa * va.w + ab * vb.w;
    A += aa + ab;
  }
  // reduce across the 4 subgroups (xor 16, 32)
#pragma unroll
  for (int m = 16; m <= 32; m <<= 1) {
    S.x += __shfl_xor(S.x, m);
    S.y += __shfl_xor(S.y, m);
    S.z += __shfl_xor(S.z, m);
    S.w += __shfl_xor(S.w, m);
    A += __shfl_xor(A, m);
  }
  float deg = (float)(e_end - s);
  float inv = 1.f / fmaxf(deg, 1.f);
  if (lane < 16) {
    float4 o = make_float4(S.x * inv, S.y * inv, S.z * inv, S.w * inv);
    ((float4*)Sp)[(size_t)n * 16 + lane] = o;
  }
  if (lane == 0) { aprime[n] = A * inv; degw[n] = deg; }
}

// ---------------- k23: t = [x|Sp] @ [Wn|Wc]^T + bn + a'*bc ; upd = t @ Wu^T + bu
// 64-node tile per block, 256 threads (4 waves). Wave w computes h in [w*32,(w+1)*32) then o in [w*16,(w+1)*16).
__global__ __launch_bounds__(256) void k23_gemm(
    const float* __restrict__ x, const float* __restrict__ Sp,
    const float* __restrict__ aprime,
    const float* __restrict__ Wn, const float* __restrict__ bn,
    const float* __restrict__ Wc, const float* __restrict__ bc,
    const float* __restrict__ Wu, const float* __restrict__ bu,
    float* __restrict__ upd) {
  __shared__ __align__(16) float u[64][132];   // [node][f 0..127], f<64: x, f>=64: Sp
  __shared__ __align__(16) float tl[64][132];  // [node][h 0..127]
  __shared__ float ap[64];
  int tid = threadIdx.x;
  int n0 = blockIdx.x * 64;

  // stage u tile (float4)
  for (int q = tid; q < 64 * 32; q += 256) {
    int b = q >> 5, c = q & 31;
    int n = n0 + b;
    float4 val = make_float4(0.f, 0.f, 0.f, 0.f);
    if (n < NN) {
      if (c < 16) val = *(const float4*)(x + (size_t)n * 64 + c * 4);
      else        val = *(const float4*)(Sp + (size_t)n * 64 + (c - 16) * 4);
    }
    *(float4*)&u[b][c * 4] = val;
  }
  if (tid < 64) {
    int n = n0 + tid;
    ap[tid] = (n < NN) ? aprime[n] : 0.f;
  }
  __syncthreads();

  int wv = tid >> 6, lane = tid & 63;
  int nm = lane & 7, nh = lane >> 3;

  // ---- t-GEMM: acc[8 nodes][4 h], K=128
  {
    float acc[8][4];
#pragma unroll
    for (int i = 0; i < 8; ++i)
#pragma unroll
      for (int j = 0; j < 4; ++j) acc[i][j] = 0.f;
    const float4* Wn4 = (const float4*)Wn;
    const float4* Wc4 = (const float4*)Wc;
    int hbase = wv * 32 + nh * 4;
#pragma unroll 4
    for (int fb = 0; fb < 16; ++fb) {  // f = fb*4 in [0,64): x part vs Wn
      float4 w[4];
#pragma unroll
      for (int j = 0; j < 4; ++j) w[j] = Wn4[(size_t)(hbase + j) * 16 + fb];
#pragma unroll
      for (int i = 0; i < 8; ++i) {
        float4 uv = *(const float4*)&u[nm + 8 * i][fb * 4];
#pragma unroll
        for (int j = 0; j < 4; ++j)
          acc[i][j] += uv.x * w[j].x + uv.y * w[j].y + uv.z * w[j].z + uv.w * w[j].w;
      }
    }
#pragma unroll 4
    for (int fb = 0; fb < 16; ++fb) {  // f = 64 + fb*4: Sp part vs Wc
      float4 w[4];
#pragma unroll
      for (int j = 0; j < 4; ++j) w[j] = Wc4[(size_t)(hbase + j) * 16 + fb];
#pragma unroll
      for (int i = 0; i < 8; ++i) {
        float4 uv = *(const float4*)&u[nm + 8 * i][64 + fb * 4];
#pragma unroll
        for (int j = 0; j < 4; ++j)
          acc[i][j] += uv.x * w[j].x + uv.y * w[j].y + uv.z * w[j].z + uv.w * w[j].w;
      }
    }
#pragma unroll
    for (int j = 0; j < 4; ++j) {
      int h = hbase + j;
      float bnv = bn[h], bcv = bc[h];
#pragma unroll
      for (int i = 0; i < 8; ++i) {
        int b = nm + 8 * i;
        tl[b][h] = acc[i][j] + bnv + ap[b] * bcv;
      }
    }
  }
  __syncthreads();

  // ---- upd-GEMM: acc[8 nodes][2 o], K=128
  {
    float acc[8][2];
#pragma unroll
    for (int i = 0; i < 8; ++i) { acc[i][0] = 0.f; acc[i][1] = 0.f; }
    const float4* Wu4 = (const float4*)Wu;
    int obase = wv * 16 + nh * 2;
#pragma unroll 4
    for (int fb = 0; fb < 32; ++fb) {
      float4 w[2];
#pragma unroll
      for (int j = 0; j < 2; ++j) w[j] = Wu4[(size_t)(obase + j) * 32 + fb];
#pragma unroll
      for (int i = 0; i < 8; ++i) {
        float4 tv = *(const float4*)&tl[nm + 8 * i][fb * 4];
#pragma unroll
        for (int j = 0; j < 2; ++j)
          acc[i][j] += tv.x * w[j].x + tv.y * w[j].y + tv.z * w[j].z + tv.w * w[j].w;
      }
    }
    float* updl = &u[0][0];  // reuse u as [64][68] upd tile
#pragma unroll
    for (int j = 0; j < 2; ++j) {
      int o = obase + j;
      float buv = bu[o];
#pragma unroll
      for (int i = 0; i < 8; ++i) {
        int b = nm + 8 * i;
        updl[b * 68 + o] = acc[i][j] + buv;
      }
    }
  }
  __syncthreads();

  // coalesced store of upd tile
  const float* updl = &u[0][0];
  for (int q = tid; q < 64 * 64; q += 256) {
    int b = q >> 6, o = q & 63;
    int n = n0 + b;
    if (n < NN) upd[(size_t)n * 64 + o] = updl[b * 68 + o];
  }
}

// ---------------- k4: KAN head. v[b][i*6+c] = {silu(upd), bases[0..4]}; out = v @ Wk^T, where(deg>0, ., x)
__global__ __launch_bounds__(256) void k4_kan(
    const float* __restrict__ upd, const float* __restrict__ Wk,
    const float* __restrict__ degw, const float* __restrict__ xin,
    const float* __restrict__ gridp, float* __restrict__ out) {
  __shared__ __align__(16) float v[32][388];
  __shared__ float degl[32];
  int tid = threadIdx.x;
  int n0 = blockIdx.x * 32;

  float g[8];
#pragma unroll
  for (int j = 0; j < 8; ++j) g[j] = gridp[j];  // all grid rows identical; use row 0
  float r1[7], r2[6];
#pragma unroll
  for (int j = 0; j < 7; ++j) r1[j] = 1.f / (g[j + 1] - g[j]);
#pragma unroll
  for (int j = 0; j < 6; ++j) r2[j] = 1.f / (g[j + 2] - g[j]);

  // stage + nonlinear transform
  for (int q = tid; q < 32 * 64; q += 256) {
    int b = q >> 6, i = q & 63;
    int n = n0 + b;
    float xv = (n < NN) ? upd[(size_t)n * 64 + i] : 0.f;
    float sil = xv / (1.f + __expf(-xv));
    float b0[7], b1[6], b2[5];
#pragma unroll
    for (int j = 0; j < 7; ++j) b0[j] = (xv >= g[j] && xv < g[j + 1]) ? 1.f : 0.f;
#pragma unroll
    for (int j = 0; j < 6; ++j)
      b1[j] = (xv - g[j]) * r1[j] * b0[j] + (g[j + 2] - xv) * r1[j + 1] * b0[j + 1];
#pragma unroll
    for (int j = 0; j < 5; ++j)
      b2[j] = (xv - g[j]) * r2[j] * b1[j] + (g[j + 3] - xv) * r2[j + 1] * b1[j + 1];
    float* dst = &v[b][i * 6];
    dst[0] = sil;
#pragma unroll
    for (int k = 0; k < 5; ++k) dst[1 + k] = b2[k];
  }
  if (tid < 32) {
    int n = n0 + tid;
    degl[tid] = (n < NN) ? degw[n] : 1.f;
  }
  __syncthreads();

  int wv = tid >> 6, lane = tid & 63;
  int nm = lane & 7, nh = lane >> 3;
  int obase = wv * 16 + nh * 2;
  float acc[4][2];
#pragma unroll
  for (int i = 0; i < 4; ++i) { acc[i][0] = 0.f; acc[i][1] = 0.f; }
  const float4* Wk4 = (const float4*)Wk;
#pragma unroll 4
  for (int kb = 0; kb < 96; ++kb) {  // K = 384
    float4 w[2];
#pragma unroll
    for (int j = 0; j < 2; ++j) w[j] = Wk4[(size_t)(obase + j) * 96 + kb];
#pragma unroll
    for (int i = 0; i < 4; ++i) {
      float4 vv = *(const float4*)&v[nm + 8 * i][kb * 4];
#pragma unroll
      for (int j = 0; j < 2; ++j)
        acc[i][j] += vv.x * w[j].x + vv.y * w[j].y + vv.z * w[j].z + vv.w * w[j].w;
    }
  }
  __syncthreads();  // everyone done reading v; reuse as out tile [32][68]

  float* ot = &v[0][0];
#pragma unroll
  for (int j = 0; j < 2; ++j) {
#pragma unroll
    for (int i = 0; i < 4; ++i) {
      int b = nm + 8 * i, o = obase + j;
      float val = acc[i][j];
      if (degl[b] <= 0.f) {
        int n = n0 + b;
        if (n < NN) val = xin[(size_t)n * 64 + o];
      }
      ot[b * 68 + o] = val;
    }
  }
  __syncthreads();
  for (int q = tid; q < 32 * 64; q += 256) {
    int b = q >> 6, o = q & 63;
    int n = n0 + b;
    if (n < NN) out[(size_t)n * 64 + o] = ot[b * 68 + o];
  }
}

extern "C" void kernel_launch(void* const* d_in, const int* in_sizes, int n_in,
                              void* d_out, int out_size, void* d_ws, size_t ws_size,
                              hipStream_t stream) {
  const float* x        = (const float*)d_in[0];
  const float* contexts = (const float*)d_in[1];
  const float* attn     = (const float*)d_in[2];
  const int*   seg      = (const int*)d_in[3];
  const float* Wn       = (const float*)d_in[4];
  const float* bn       = (const float*)d_in[5];
  const float* Wc       = (const float*)d_in[6];
  const float* bc       = (const float*)d_in[7];
  const float* Wu       = (const float*)d_in[8];
  const float* bu       = (const float*)d_in[9];
  const float* base_w   = (const float*)d_in[10];
  const float* spline_w = (const float*)d_in[11];
  const float* scaler   = (const float*)d_in[12];
  const float* gridp    = (const float*)d_in[13];
  float* out = (float*)d_out;

  float* ws     = (float*)d_ws;
  float* Sp     = ws;                  // N*64
  float* aprime = Sp + 3200000;        // N
  float* degw   = aprime + 50000;      // N
  float* upd    = degw + 50000;        // N*64
  float* Wk     = upd + 3200000;       // 64*384 = 24576
  int*   off    = (int*)(Wk + 24576);  // N+1

  k0_pack<<<16, 256, 0, stream>>>(base_w, spline_w, scaler, Wk);
  k_off<<<3125, 256, 0, stream>>>(seg, off);
  k1_edge_agg<<<12500, 256, 0, stream>>>(contexts, attn, off, Sp, aprime, degw);
  k23_gemm<<<782, 256, 0, stream>>>(x, Sp, aprime, Wn, bn, Wc, bc, Wu, bu, upd);
  k4_kan<<<1563, 256, 0, stream>>>(upd, Wk, degw, x, gridp, out);
}